// Round 11
// baseline (91.744 us; speedup 1.0000x reference)
//
#include <hip/hip_runtime.h>

// GraphSAGE 2-layer, N=500000, E=5000000.
// Pipeline: k_pre (cursor init + packed-quant qx) -> k_part (bucket partition
// by dst>>10, register-staged edges, LDS counting sort, coalesced flush into
// per-(bucket,group) regions) -> k_agg1 (LDS u64 bins + fused node MLP) ->
// k_agg2 (LDS u32 bins + fused sigmoid).
// Round-11: claim cursors split 8 ways by blockIdx&7 (claim chain per line
// 245 -> ~31 serialized memory-side RMWs); shfl 2-level scan (18 barriers ->
// 2); sq u16 (1MB gather array); (ga,t0a) packed float2.
// All aggregation fixed-point integer => deterministic; quant err ~2e-3.

static constexpr int ABLOCK = 512;           // agg kernels block size (8 waves)
static constexpr int PBLOCK = 1024;          // k_part block size
static constexpr int KITER  = 5;             // int4 groups per thread
static constexpr int CHUNK  = PBLOCK * 4 * KITER;   // 20480 edges per block
static constexpr int BUCKET_BITS = 10;
static constexpr int BUCKET_NODES = 1 << BUCKET_BITS;   // 1024
static constexpr int MAXNB = 512;            // >= NB = 489
static constexpr int NGRP = 8;               // claim-cursor groups
static constexpr int GCAP = 2048;            // per-(bucket,group) capacity
                                             // mean 1290, sigma~36 -> +21 sigma
static constexpr int CSTRIDE = 16;           // cursor padding: 64B

static constexpr float S1 = 2048.0f;         // layer-1 quant 2^11, bias +8 (u16)
static constexpr float IS1 = 1.0f / 2048.0f;
static constexpr long long B1 = 8LL * 2048LL;     // 16384 per edge
static constexpr float S2 = 256.0f;          // layer-2 quant 2^8, bias +128 (u16)
static constexpr float IS2 = 1.0f / 256.0f;

// ---- k_pre: cursor init + pack x into qx (q0<<16|q1), u16 quant ----
__global__ __launch_bounds__(256) void k_pre(
    const float* __restrict__ x, unsigned* __restrict__ qx,
    unsigned* __restrict__ cursor, int N, int NBG)
{
    int i = blockIdx.x * 256 + threadIdx.x;
    if (i < NBG) cursor[(size_t)i * CSTRIDE] = (unsigned)i * (unsigned)GCAP;
    if (i >= N) return;
    float2 xv = *reinterpret_cast<const float2*>(x + 2 * (size_t)i);
    float f0 = fminf(fmaxf((xv.x + 8.0f) * S1, 0.0f), 65535.0f);
    float f1 = fminf(fmaxf((xv.y + 8.0f) * S1, 0.0f), 65535.0f);
    unsigned q0 = (unsigned)__float2int_rn(f0);
    unsigned q1 = (unsigned)__float2int_rn(f1);
    qx[i] = (q0 << 16) | q1;
}

__global__ __launch_bounds__(PBLOCK) void k_part(
    const int* __restrict__ src, const int* __restrict__ dst,
    unsigned* __restrict__ cursor, unsigned* __restrict__ entries,
    int E, int NB)
{
    __shared__ unsigned sorted[CHUNK];
    __shared__ unsigned hist[MAXNB];
    __shared__ unsigned loc[MAXNB];
    __shared__ unsigned base[MAXNB];
    __shared__ unsigned wsum[8];
    const int tid = threadIdx.x;
    const unsigned g = blockIdx.x & (NGRP - 1);
    const int e0 = (int)blockIdx.x * CHUNK;
    const int e1 = min(e0 + CHUNK, E);
    const int4* dst4 = reinterpret_cast<const int4*>(dst + e0);
    const int4* src4 = reinterpret_cast<const int4*>(src + e0);

    // ---- load this thread's 5 int4 groups of (src,dst) into registers ----
    int4 dR[KITER], sR[KITER];
#pragma unroll
    for (int k = 0; k < KITER; ++k) {
        int gi = tid + k * PBLOCK;               // int4-group index
        int e = e0 + 4 * gi;
        if (e + 3 < e1) {
            dR[k] = dst4[gi];
            sR[k] = src4[gi];
        } else {
            dR[k] = make_int4(-1, -1, -1, -1);   // sentinel: invalid
            sR[k] = make_int4(0, 0, 0, 0);
#pragma unroll
            for (int j = 0; j < 4; ++j) {
                if (e + j < e1) {
                    (&dR[k].x)[j] = dst[e + j];
                    (&sR[k].x)[j] = src[e + j];
                }
            }
        }
    }

    for (int b = tid; b < MAXNB; b += PBLOCK) hist[b] = 0;
    __syncthreads();

    // ---- pass 1: histogram from registers ----
    #define HIST1(dv) { unsigned du_ = (unsigned)(dv); \
        if (du_ != 0xFFFFFFFFu) atomicAdd(&hist[du_ >> BUCKET_BITS], 1u); }
#pragma unroll
    for (int k = 0; k < KITER; ++k) {
        HIST1(dR[k].x) HIST1(dR[k].y) HIST1(dR[k].z) HIST1(dR[k].w)
    }
    #undef HIST1
    __syncthreads();

    // ---- 2-level exclusive scan (shfl within wave + serial wave offsets) ---
    {
        unsigned lane6 = (unsigned)tid & 63u, wv = (unsigned)tid >> 6;
        unsigned hv = (tid < NB) ? hist[tid] : 0u;
        if (tid < 512) {
            unsigned v = hv;
#pragma unroll
            for (int off = 1; off < 64; off <<= 1) {
                unsigned u = __shfl_up(v, off);
                if (lane6 >= (unsigned)off) v += u;
            }
            if (lane6 == 63) wsum[wv] = v;
            if (tid < NB) loc[tid] = v - hv;     // exclusive within wave
        }
        __syncthreads();
        if (tid == 0) {
            unsigned acc = 0;
#pragma unroll
            for (int k = 0; k < 8; ++k) { unsigned t2 = wsum[k]; wsum[k] = acc; acc += t2; }
        }
        __syncthreads();
        if (tid < NB) loc[tid] += wsum[wv];
    }

    // ---- claim spans in this block's group region (chain/line ~31 not 245) --
    if (tid < NB) {
        int b = tid + (int)(blockIdx.x % (unsigned)NB);
        if (b >= NB) b -= NB;
        base[b] = atomicAdd(&cursor[((size_t)b * NGRP + g) * CSTRIDE], hist[b]);
    }
    __syncthreads();
    for (int b = tid; b < MAXNB; b += PBLOCK) hist[b] = 0;   // reuse as ranks
    __syncthreads();

    // ---- pass 2: scatter from registers into LDS-sorted order ----
    #define SCAT1(dv, sv) { unsigned du_ = (unsigned)(dv); \
        if (du_ != 0xFFFFFFFFu) { \
            unsigned bk_ = du_ >> BUCKET_BITS; \
            unsigned r_ = atomicAdd(&hist[bk_], 1u); \
            sorted[loc[bk_] + r_] = ((unsigned)(sv) << BUCKET_BITS) | (du_ & (BUCKET_NODES - 1)); } }
#pragma unroll
    for (int k = 0; k < KITER; ++k) {
        SCAT1(dR[k].x, sR[k].x) SCAT1(dR[k].y, sR[k].y)
        SCAT1(dR[k].z, sR[k].z) SCAT1(dR[k].w, sR[k].w)
    }
    #undef SCAT1
    __syncthreads();

    // ---- pass 3: coalesced flush, one bucket run per wave ----
    const int wave = tid >> 6, lane = tid & 63;
    const int nw = PBLOCK >> 6;
    const int off = (int)(blockIdx.x % (unsigned)NB);
    for (int j = wave; j < NB; j += nw) {
        int b = j + off;
        if (b >= NB) b -= NB;
        unsigned cnt = hist[b];
        if (cnt == 0) continue;
        unsigned lo = loc[b], ba = base[b];
        unsigned lim = ((unsigned)b * NGRP + g + 1u) * (unsigned)GCAP;
        if (ba >= lim) continue;                 // overflow guard (stat. impossible)
        cnt = min(cnt, lim - ba);
        for (unsigned i = lane; i < cnt; i += 64)
            entries[ba + i] = sorted[lo + i];
    }
}

#define PK(q) ((1ULL << 56) | ((unsigned long long)((q) >> 16) << 28) \
               | (unsigned long long)((q) & 0xFFFFu))

__global__ __launch_bounds__(ABLOCK) void k_agg1(
    const unsigned* __restrict__ entries, const unsigned* __restrict__ cursor,
    const unsigned* __restrict__ qx, const float* __restrict__ x,
    const float* __restrict__ W1l, const float* __restrict__ b1,
    const float* __restrict__ W1r, const float* __restrict__ W2l,
    const float* __restrict__ W2r, const float* __restrict__ b2,
    unsigned short* __restrict__ sq, float2* __restrict__ tg,
    int N)
{
    __shared__ unsigned long long qs[BUCKET_NODES];  // deg[63:56]|q0[55:28]|q1[27:0]
    int bk = blockIdx.x;
    for (int i = threadIdx.x; i < BUCKET_NODES; i += ABLOCK) qs[i] = 0ULL;
    __syncthreads();

    // one wave per group segment; 8-deep batched gathers within the wave
    {
        const unsigned wv = (unsigned)threadIdx.x >> 6;
        const unsigned lane = (unsigned)threadIdx.x & 63u;
        const unsigned seg = (unsigned)bk * NGRP + wv;
        const unsigned base0 = seg * (unsigned)GCAP;
        unsigned end = min(cursor[(size_t)seg * CSTRIDE], base0 + (unsigned)GCAP);
        unsigned len = end - base0;
        unsigned t = 0;
        for (; t + 512 <= len; t += 512) {
            const uint4* p = reinterpret_cast<const uint4*>(entries + base0 + t + (lane << 3));
            uint4 a = p[0];
            uint4 b = p[1];
            unsigned g0 = qx[a.x >> BUCKET_BITS];
            unsigned g1 = qx[a.y >> BUCKET_BITS];
            unsigned g2 = qx[a.z >> BUCKET_BITS];
            unsigned g3 = qx[a.w >> BUCKET_BITS];
            unsigned g4 = qx[b.x >> BUCKET_BITS];
            unsigned g5 = qx[b.y >> BUCKET_BITS];
            unsigned g6 = qx[b.z >> BUCKET_BITS];
            unsigned g7 = qx[b.w >> BUCKET_BITS];
            atomicAdd(&qs[a.x & (BUCKET_NODES - 1)], PK(g0));
            atomicAdd(&qs[a.y & (BUCKET_NODES - 1)], PK(g1));
            atomicAdd(&qs[a.z & (BUCKET_NODES - 1)], PK(g2));
            atomicAdd(&qs[a.w & (BUCKET_NODES - 1)], PK(g3));
            atomicAdd(&qs[b.x & (BUCKET_NODES - 1)], PK(g4));
            atomicAdd(&qs[b.y & (BUCKET_NODES - 1)], PK(g5));
            atomicAdd(&qs[b.z & (BUCKET_NODES - 1)], PK(g6));
            atomicAdd(&qs[b.w & (BUCKET_NODES - 1)], PK(g7));
        }
        for (unsigned u = t + lane; u < len; u += 64) {
            unsigned en = entries[base0 + u];
            unsigned gq = qx[en >> BUCKET_BITS];
            atomicAdd(&qs[en & (BUCKET_NODES - 1)], PK(gq));
        }
    }
    __syncthreads();

    int nodebase = bk << BUCKET_BITS;
    for (int il = threadIdx.x; il < BUCKET_NODES; il += ABLOCK) {
        int i = nodebase + il;
        if (i >= N) continue;
        unsigned long long v = qs[il];
        int deg = (int)(v >> 56);
        long long q0 = (long long)((v >> 28) & 0xFFFFFFFULL);
        long long q1 = (long long)(v & 0xFFFFFFFULL);
        long long bias = (long long)deg * B1;
        float inv = 1.0f / (float)max(deg, 1);
        float m0 = (float)(q0 - bias) * IS1 * inv;
        float m1 = (float)(q1 - bias) * IS1 * inv;
        float2 xv = *reinterpret_cast<const float2*>(x + 2 * (size_t)i);
        float s = 0.0f, t0 = b2[0];
#pragma unroll
        for (int o = 0; o < 16; ++o) {
            float h = m0 * W1l[2 * o] + m1 * W1l[2 * o + 1] + b1[o]
                    + xv.x * W1r[2 * o] + xv.y * W1r[2 * o + 1];
            h = fmaxf(h, 0.0f);
            s  += h * W2l[o];
            t0 += h * W2r[o];
        }
        // mean_s = sbin*IS2*inv - 128*(deg>0)
        float fq = fminf(fmaxf((s + 128.0f) * S2, 0.0f), 65535.0f);
        sq[i] = (unsigned short)__float2int_rn(fq);
        tg[i] = make_float2(IS2 * inv, t0 - (deg > 0 ? 128.0f : 0.0f));
    }
}

__global__ __launch_bounds__(ABLOCK) void k_agg2(
    const unsigned* __restrict__ entries, const unsigned* __restrict__ cursor,
    const unsigned short* __restrict__ sq,
    const float2* __restrict__ tg,
    float* __restrict__ out, int N)
{
    __shared__ unsigned sbin[BUCKET_NODES];
    int bk = blockIdx.x;
    for (int i = threadIdx.x; i < BUCKET_NODES; i += ABLOCK) sbin[i] = 0;
    __syncthreads();

    {
        const unsigned wv = (unsigned)threadIdx.x >> 6;
        const unsigned lane = (unsigned)threadIdx.x & 63u;
        const unsigned seg = (unsigned)bk * NGRP + wv;
        const unsigned base0 = seg * (unsigned)GCAP;
        unsigned end = min(cursor[(size_t)seg * CSTRIDE], base0 + (unsigned)GCAP);
        unsigned len = end - base0;
        unsigned t = 0;
        for (; t + 512 <= len; t += 512) {
            const uint4* p = reinterpret_cast<const uint4*>(entries + base0 + t + (lane << 3));
            uint4 a = p[0];
            uint4 b = p[1];
            unsigned v0 = sq[a.x >> BUCKET_BITS];
            unsigned v1 = sq[a.y >> BUCKET_BITS];
            unsigned v2 = sq[a.z >> BUCKET_BITS];
            unsigned v3 = sq[a.w >> BUCKET_BITS];
            unsigned v4 = sq[b.x >> BUCKET_BITS];
            unsigned v5 = sq[b.y >> BUCKET_BITS];
            unsigned v6 = sq[b.z >> BUCKET_BITS];
            unsigned v7 = sq[b.w >> BUCKET_BITS];
            atomicAdd(&sbin[a.x & (BUCKET_NODES - 1)], v0);
            atomicAdd(&sbin[a.y & (BUCKET_NODES - 1)], v1);
            atomicAdd(&sbin[a.z & (BUCKET_NODES - 1)], v2);
            atomicAdd(&sbin[a.w & (BUCKET_NODES - 1)], v3);
            atomicAdd(&sbin[b.x & (BUCKET_NODES - 1)], v4);
            atomicAdd(&sbin[b.y & (BUCKET_NODES - 1)], v5);
            atomicAdd(&sbin[b.z & (BUCKET_NODES - 1)], v6);
            atomicAdd(&sbin[b.w & (BUCKET_NODES - 1)], v7);
        }
        for (unsigned u = t + lane; u < len; u += 64) {
            unsigned en = entries[base0 + u];
            atomicAdd(&sbin[en & (BUCKET_NODES - 1)], (unsigned)sq[en >> BUCKET_BITS]);
        }
    }
    __syncthreads();

    int nodebase = bk << BUCKET_BITS;
    for (int il = threadIdx.x; il < BUCKET_NODES; il += ABLOCK) {
        int i = nodebase + il;
        if (i >= N) continue;
        float2 tgv = tg[i];
        float t = (float)(int)sbin[il] * tgv.x + tgv.y;
        out[i] = 1.0f / (1.0f + expf(-t));
    }
}

// ------------------- fallback (simple atomic path, 10MB ws) -----------------
__global__ __launch_bounds__(256) void k_scatter1_fb(
    const int* __restrict__ src, const int* __restrict__ dst,
    const float* __restrict__ x, float* __restrict__ agg1, float* __restrict__ deg, int E)
{
    int stride = gridDim.x * blockDim.x;
    for (int e = blockIdx.x * blockDim.x + threadIdx.x; e < E; e += stride) {
        int s = src[e], d = dst[e];
        float2 xv = *reinterpret_cast<const float2*>(x + 2 * (size_t)s);
        unsafeAtomicAdd(&agg1[2 * (size_t)d + 0], xv.x);
        unsafeAtomicAdd(&agg1[2 * (size_t)d + 1], xv.y);
        unsafeAtomicAdd(&deg[d], 1.0f);
    }
}
__global__ __launch_bounds__(256) void k_node1_fb(
    const float* __restrict__ x, const float* __restrict__ agg1, const float* __restrict__ deg,
    const float* __restrict__ W1l, const float* __restrict__ b1,
    const float* __restrict__ W1r, const float* __restrict__ W2l,
    float* __restrict__ sval, int N)
{
    int i = blockIdx.x * blockDim.x + threadIdx.x;
    if (i >= N) return;
    float inv = 1.0f / fmaxf(deg[i], 1.0f);
    float2 a = *reinterpret_cast<const float2*>(agg1 + 2 * (size_t)i);
    float m0 = a.x * inv, m1 = a.y * inv;
    float2 xv = *reinterpret_cast<const float2*>(x + 2 * (size_t)i);
    float s = 0.0f;
#pragma unroll
    for (int o = 0; o < 16; ++o) {
        float h = m0 * W1l[2 * o] + m1 * W1l[2 * o + 1] + b1[o]
                + xv.x * W1r[2 * o] + xv.y * W1r[2 * o + 1];
        s += fmaxf(h, 0.0f) * W2l[o];
    }
    sval[i] = s;
}
__global__ __launch_bounds__(256) void k_scatter2_fb(
    const int* __restrict__ src, const int* __restrict__ dst,
    const float* __restrict__ sval, float* __restrict__ agg_s, int E)
{
    int stride = gridDim.x * blockDim.x;
    for (int e = blockIdx.x * blockDim.x + threadIdx.x; e < E; e += stride)
        unsafeAtomicAdd(&agg_s[dst[e]], sval[src[e]]);
}
__global__ __launch_bounds__(256) void k_node2_fb(
    const float* __restrict__ x, const float* __restrict__ agg1, const float* __restrict__ deg,
    const float* __restrict__ agg_s,
    const float* __restrict__ W1l, const float* __restrict__ b1,
    const float* __restrict__ W1r, const float* __restrict__ W2r, const float* __restrict__ b2,
    float* __restrict__ out, int N)
{
    int i = blockIdx.x * blockDim.x + threadIdx.x;
    if (i >= N) return;
    float inv = 1.0f / fmaxf(deg[i], 1.0f);
    float2 a = *reinterpret_cast<const float2*>(agg1 + 2 * (size_t)i);
    float m0 = a.x * inv, m1 = a.y * inv;
    float2 xv = *reinterpret_cast<const float2*>(x + 2 * (size_t)i);
    float t = agg_s[i] * inv + b2[0];
#pragma unroll
    for (int o = 0; o < 16; ++o) {
        float h = m0 * W1l[2 * o] + m1 * W1l[2 * o + 1] + b1[o]
                + xv.x * W1r[2 * o] + xv.y * W1r[2 * o + 1];
        t += fmaxf(h, 0.0f) * W2r[o];
    }
    out[i] = 1.0f / (1.0f + expf(-t));
}

extern "C" void kernel_launch(void* const* d_in, const int* in_sizes, int n_in,
                              void* d_out, int out_size, void* d_ws, size_t ws_size,
                              hipStream_t stream) {
    const float* x   = (const float*)d_in[0];
    const int*   ei  = (const int*)d_in[1];
    const float* W1l = (const float*)d_in[2];
    const float* b1  = (const float*)d_in[3];
    const float* W1r = (const float*)d_in[4];
    const float* W2l = (const float*)d_in[5];
    const float* b2  = (const float*)d_in[6];
    const float* W2r = (const float*)d_in[7];

    const int N = in_sizes[0] / 2;
    const int E = in_sizes[1] / 2;
    const int* src = ei;
    const int* dst = ei + (size_t)E;
    float* out = (float*)d_out;

    const int NB = (N + BUCKET_NODES - 1) >> BUCKET_BITS;   // 489
    const int NBG = NB * NGRP;                              // 3912
    const int pblocks = (E + CHUNK - 1) / CHUNK;            // 245

    // ws: cursor[NBG*16] | entries[NBG*GCAP] | sq u16[N] | tg float2[N] | qx[N]
    size_t needed = (size_t)MAXNB * NGRP * CSTRIDE * 4
                  + (size_t)NBG * GCAP * 4
                  + ((size_t)N * 2 + 3) / 4 * 4
                  + (size_t)N * 8 + (size_t)N * 4 + 256;
    if (NB <= MAXNB && NB <= PBLOCK && ws_size >= needed) {
        unsigned* cursor   = (unsigned*)d_ws;
        unsigned* entries  = cursor + (size_t)MAXNB * NGRP * CSTRIDE;
        unsigned short* sq = (unsigned short*)(entries + (size_t)NBG * GCAP);
        float2*   tg       = (float2*)((char*)sq + (((size_t)N * 2 + 7) & ~7ull));
        unsigned* qx       = (unsigned*)(tg + N);

        k_pre<<<(N + 255) / 256, 256, 0, stream>>>(x, qx, cursor, N, NBG);
        k_part<<<pblocks, PBLOCK, 0, stream>>>(src, dst, cursor, entries, E, NB);
        k_agg1<<<NB, ABLOCK, 0, stream>>>(entries, cursor, qx, x, W1l, b1, W1r,
                                          W2l, W2r, b2, sq, tg, N);
        k_agg2<<<NB, ABLOCK, 0, stream>>>(entries, cursor, sq, tg, out, N);
    } else {
        float* agg1  = (float*)d_ws;
        float* deg   = agg1 + 2 * (size_t)N;
        float* agg_s = deg + (size_t)N;
        float* sval  = agg_s + (size_t)N;
        hipMemsetAsync(d_ws, 0, 4 * (size_t)N * sizeof(float), stream);
        const int eblocks = 2048, nblocks = (N + 255) / 256;
        k_scatter1_fb<<<eblocks, 256, 0, stream>>>(src, dst, x, agg1, deg, E);
        k_node1_fb<<<nblocks, 256, 0, stream>>>(x, agg1, deg, W1l, b1, W1r, W2l, sval, N);
        k_scatter2_fb<<<eblocks, 256, 0, stream>>>(src, dst, sval, agg_s, E);
        k_node2_fb<<<nblocks, 256, 0, stream>>>(x, agg1, deg, agg_s, W1l, b1, W1r, W2r, b2, out, N);
    }
}

// Round 12
// 90.207 us; speedup vs baseline: 1.0170x; 1.0170x over previous
//
#include <hip/hip_runtime.h>

// GraphSAGE 2-layer, N=500000, E=5000000.
// Pipeline: k_pre (cursor init + packed-quant qx) -> k_part (bucket partition
// by dst>>10, register-staged edges, LDS counting sort with 8x-REPLICATED
// counters, coalesced run flush) -> k_agg1 (LDS u64 bins + fused node MLP)
// -> k_agg2 (LDS u32 bins + fused sigmoid).
// Round-12: theory = pipeline is LDS-atomic-RMW bound (~25M serializing LDS
// ops; 7 rounds of memory/occupancy knobs all flat). k_part's histogram and
// rank-claim counters replicated 8x (one per 128-thread group, +1 padding
// word per row to spread banks) -> same-address RMW chains cut ~8x.
// Aggs: R10's proven block-wide 8-deep batching; sq u16; (ga,t0) float2.
// All aggregation fixed-point integer => deterministic; quant err ~2e-3.

static constexpr int ABLOCK = 512;           // agg kernels block size
static constexpr int PBLOCK = 1024;          // k_part block size
static constexpr int KITER  = 5;             // int4 groups per thread
static constexpr int CHUNK  = PBLOCK * 4 * KITER;   // 20480 edges per block
static constexpr int BUCKET_BITS = 10;
static constexpr int BUCKET_NODES = 1 << BUCKET_BITS;   // 1024
static constexpr int MAXNB = 512;            // >= NB = 489
static constexpr int NR = 8;                 // LDS counter replicas
static constexpr int CAP = 16384;            // mean 10240, sigma~101 -> +40 sigma
static constexpr int CSTRIDE = 16;           // cursor padding: 64B

static constexpr float S1 = 2048.0f;         // layer-1 quant 2^11, bias +8 (u16)
static constexpr float IS1 = 1.0f / 2048.0f;
static constexpr long long B1 = 8LL * 2048LL;     // 16384 per edge
static constexpr float S2 = 256.0f;          // layer-2 quant 2^8, bias +128 (u16)
static constexpr float IS2 = 1.0f / 256.0f;

// ---- k_pre: cursor init + pack x into qx (q0<<16|q1), u16 quant ----
__global__ __launch_bounds__(256) void k_pre(
    const float* __restrict__ x, unsigned* __restrict__ qx,
    unsigned* __restrict__ cursor, int N, int NB)
{
    int i = blockIdx.x * 256 + threadIdx.x;
    if (i < NB) cursor[(size_t)i * CSTRIDE] = (unsigned)i * (unsigned)CAP;
    if (i >= N) return;
    float2 xv = *reinterpret_cast<const float2*>(x + 2 * (size_t)i);
    float f0 = fminf(fmaxf((xv.x + 8.0f) * S1, 0.0f), 65535.0f);
    float f1 = fminf(fmaxf((xv.y + 8.0f) * S1, 0.0f), 65535.0f);
    unsigned q0 = (unsigned)__float2int_rn(f0);
    unsigned q1 = (unsigned)__float2int_rn(f1);
    qx[i] = (q0 << 16) | q1;
}

__global__ __launch_bounds__(PBLOCK) void k_part(
    const int* __restrict__ src, const int* __restrict__ dst,
    unsigned* __restrict__ cursor, unsigned* __restrict__ entries,
    int E, int NB)
{
    __shared__ unsigned sorted[CHUNK];           // 80 KB
    __shared__ unsigned histR[NR][MAXNB + 1];    // 16 KB, +1 pad spreads banks
    __shared__ unsigned offR[NR][MAXNB + 1];     // 16 KB
    __shared__ unsigned hist[MAXNB];             // totals
    __shared__ unsigned loc[MAXNB];
    __shared__ unsigned base[MAXNB];
    __shared__ unsigned wsum[8];
    const int tid = threadIdx.x;
    const int g = tid >> 7;                      // 128-thread replica group
    const int e0 = (int)blockIdx.x * CHUNK;
    const int e1 = min(e0 + CHUNK, E);
    const int4* dst4 = reinterpret_cast<const int4*>(dst + e0);
    const int4* src4 = reinterpret_cast<const int4*>(src + e0);

    // ---- load this thread's 5 int4 groups of (src,dst) into registers ----
    int4 dR[KITER], sR[KITER];
#pragma unroll
    for (int k = 0; k < KITER; ++k) {
        int gi = tid + k * PBLOCK;               // int4-group index
        int e = e0 + 4 * gi;
        if (e + 3 < e1) {
            dR[k] = dst4[gi];
            sR[k] = src4[gi];
        } else {
            dR[k] = make_int4(-1, -1, -1, -1);   // sentinel: invalid
            sR[k] = make_int4(0, 0, 0, 0);
#pragma unroll
            for (int j = 0; j < 4; ++j) {
                if (e + j < e1) {
                    (&dR[k].x)[j] = dst[e + j];
                    (&sR[k].x)[j] = src[e + j];
                }
            }
        }
    }

    for (int i = tid; i < NR * (MAXNB + 1); i += PBLOCK)
        (&histR[0][0])[i] = 0;
    __syncthreads();

    // ---- pass 1: histogram into this group's replica ----
    #define HIST1(dv) { unsigned du_ = (unsigned)(dv); \
        if (du_ != 0xFFFFFFFFu) atomicAdd(&histR[g][du_ >> BUCKET_BITS], 1u); }
#pragma unroll
    for (int k = 0; k < KITER; ++k) {
        HIST1(dR[k].x) HIST1(dR[k].y) HIST1(dR[k].z) HIST1(dR[k].w)
    }
    #undef HIST1
    __syncthreads();

    // ---- totals + per-group offsets (thread b serial over 8 replicas) ----
    if (tid < NB) {
        unsigned acc = 0;
#pragma unroll
        for (int k = 0; k < NR; ++k) { offR[k][tid] = acc; acc += histR[k][tid]; }
        hist[tid] = acc;
    }
    __syncthreads();

    // ---- 2-level exclusive scan (shfl within wave + serial wave offsets) ---
    {
        unsigned lane6 = (unsigned)tid & 63u, wv = (unsigned)tid >> 6;
        if (tid < 512) {
            unsigned hv = (tid < NB) ? hist[tid] : 0u;
            unsigned v = hv;
#pragma unroll
            for (int off = 1; off < 64; off <<= 1) {
                unsigned u = __shfl_up(v, off);
                if (lane6 >= (unsigned)off) v += u;
            }
            if (lane6 == 63) wsum[wv] = v;
            if (tid < NB) loc[tid] = v - hv;     // exclusive within wave
        }
        __syncthreads();
        if (tid == 0) {
            unsigned acc = 0;
#pragma unroll
            for (int k = 0; k < 8; ++k) { unsigned t2 = wsum[k]; wsum[k] = acc; acc += t2; }
        }
        __syncthreads();
        if (tid < NB) loc[tid] += wsum[wv];
    }

    // ---- claim contiguous global spans (rotated; cursor lines padded) ----
    if (tid < NB) {
        int b = tid + (int)(blockIdx.x % (unsigned)NB);
        if (b >= NB) b -= NB;
        base[b] = atomicAdd(&cursor[(size_t)b * CSTRIDE], hist[b]);
    }
    __syncthreads();
    for (int i = tid; i < NR * (MAXNB + 1); i += PBLOCK)
        (&histR[0][0])[i] = 0;                   // reuse replicas as ranks
    __syncthreads();

    // ---- pass 2: scatter from registers, rank via this group's replica ----
    #define SCAT1(dv, sv) { unsigned du_ = (unsigned)(dv); \
        if (du_ != 0xFFFFFFFFu) { \
            unsigned bk_ = du_ >> BUCKET_BITS; \
            unsigned r_ = atomicAdd(&histR[g][bk_], 1u); \
            sorted[loc[bk_] + offR[g][bk_] + r_] = \
                ((unsigned)(sv) << BUCKET_BITS) | (du_ & (BUCKET_NODES - 1)); } }
#pragma unroll
    for (int k = 0; k < KITER; ++k) {
        SCAT1(dR[k].x, sR[k].x) SCAT1(dR[k].y, sR[k].y)
        SCAT1(dR[k].z, sR[k].z) SCAT1(dR[k].w, sR[k].w)
    }
    #undef SCAT1
    __syncthreads();

    // ---- pass 3: coalesced flush, one bucket run per wave ----
    const int wave = tid >> 6, lane = tid & 63;
    const int nw = PBLOCK >> 6;
    const int off = (int)(blockIdx.x % (unsigned)NB);
    for (int j = wave; j < NB; j += nw) {
        int b = j + off;
        if (b >= NB) b -= NB;
        unsigned cnt = hist[b];
        if (cnt == 0) continue;
        unsigned lo = loc[b], ba = base[b];
        unsigned lim = (unsigned)(b + 1) * (unsigned)CAP;
        if (ba >= lim) continue;                 // overflow guard (stat. impossible)
        cnt = min(cnt, lim - ba);
        for (unsigned i = lane; i < cnt; i += 64)
            entries[ba + i] = sorted[lo + i];
    }
}

#define PK(q) ((1ULL << 56) | ((unsigned long long)((q) >> 16) << 28) \
               | (unsigned long long)((q) & 0xFFFFu))

__global__ __launch_bounds__(ABLOCK) void k_agg1(
    const unsigned* __restrict__ entries, const unsigned* __restrict__ cursor,
    const unsigned* __restrict__ qx, const float* __restrict__ x,
    const float* __restrict__ W1l, const float* __restrict__ b1,
    const float* __restrict__ W1r, const float* __restrict__ W2l,
    const float* __restrict__ W2r, const float* __restrict__ b2,
    unsigned short* __restrict__ sq, float2* __restrict__ tg,
    int N)
{
    __shared__ unsigned long long qs[BUCKET_NODES];  // deg[63:56]|q0[55:28]|q1[27:0]
    int bk = blockIdx.x;
    for (int i = threadIdx.x; i < BUCKET_NODES; i += ABLOCK) qs[i] = 0ULL;
    __syncthreads();

    unsigned start = (unsigned)bk * (unsigned)CAP;
    unsigned end = min(cursor[(size_t)bk * CSTRIDE], start + (unsigned)CAP);
    unsigned n = end - start;
    unsigned n8 = n >> 3;                        // groups of 8 entries
    const uint4* e4 = reinterpret_cast<const uint4*>(entries + start);

    // batched: 2x uint4 entry load -> 8 gathers in flight -> 8 LDS atomics
    for (unsigned t = threadIdx.x; t < n8; t += ABLOCK) {
        uint4 a = e4[2 * t];
        uint4 b = e4[2 * t + 1];
        unsigned g0 = qx[a.x >> BUCKET_BITS];
        unsigned g1 = qx[a.y >> BUCKET_BITS];
        unsigned g2 = qx[a.z >> BUCKET_BITS];
        unsigned g3 = qx[a.w >> BUCKET_BITS];
        unsigned g4 = qx[b.x >> BUCKET_BITS];
        unsigned g5 = qx[b.y >> BUCKET_BITS];
        unsigned g6 = qx[b.z >> BUCKET_BITS];
        unsigned g7 = qx[b.w >> BUCKET_BITS];
        atomicAdd(&qs[a.x & (BUCKET_NODES - 1)], PK(g0));
        atomicAdd(&qs[a.y & (BUCKET_NODES - 1)], PK(g1));
        atomicAdd(&qs[a.z & (BUCKET_NODES - 1)], PK(g2));
        atomicAdd(&qs[a.w & (BUCKET_NODES - 1)], PK(g3));
        atomicAdd(&qs[b.x & (BUCKET_NODES - 1)], PK(g4));
        atomicAdd(&qs[b.y & (BUCKET_NODES - 1)], PK(g5));
        atomicAdd(&qs[b.z & (BUCKET_NODES - 1)], PK(g6));
        atomicAdd(&qs[b.w & (BUCKET_NODES - 1)], PK(g7));
    }
    for (unsigned t = start + (n8 << 3) + threadIdx.x; t < end; t += ABLOCK) {
        unsigned en = entries[t];
        unsigned gq = qx[en >> BUCKET_BITS];
        atomicAdd(&qs[en & (BUCKET_NODES - 1)], PK(gq));
    }
    __syncthreads();

    int nodebase = bk << BUCKET_BITS;
    for (int il = threadIdx.x; il < BUCKET_NODES; il += ABLOCK) {
        int i = nodebase + il;
        if (i >= N) continue;
        unsigned long long v = qs[il];
        int deg = (int)(v >> 56);
        long long q0 = (long long)((v >> 28) & 0xFFFFFFFULL);
        long long q1 = (long long)(v & 0xFFFFFFFULL);
        long long bias = (long long)deg * B1;
        float inv = 1.0f / (float)max(deg, 1);
        float m0 = (float)(q0 - bias) * IS1 * inv;
        float m1 = (float)(q1 - bias) * IS1 * inv;
        float2 xv = *reinterpret_cast<const float2*>(x + 2 * (size_t)i);
        float s = 0.0f, t0 = b2[0];
#pragma unroll
        for (int o = 0; o < 16; ++o) {
            float h = m0 * W1l[2 * o] + m1 * W1l[2 * o + 1] + b1[o]
                    + xv.x * W1r[2 * o] + xv.y * W1r[2 * o + 1];
            h = fmaxf(h, 0.0f);
            s  += h * W2l[o];
            t0 += h * W2r[o];
        }
        // mean_s = sbin*IS2*inv - 128*(deg>0)
        float fq = fminf(fmaxf((s + 128.0f) * S2, 0.0f), 65535.0f);
        sq[i] = (unsigned short)__float2int_rn(fq);
        tg[i] = make_float2(IS2 * inv, t0 - (deg > 0 ? 128.0f : 0.0f));
    }
}

__global__ __launch_bounds__(ABLOCK) void k_agg2(
    const unsigned* __restrict__ entries, const unsigned* __restrict__ cursor,
    const unsigned short* __restrict__ sq,
    const float2* __restrict__ tg,
    float* __restrict__ out, int N)
{
    __shared__ unsigned sbin[BUCKET_NODES];
    int bk = blockIdx.x;
    for (int i = threadIdx.x; i < BUCKET_NODES; i += ABLOCK) sbin[i] = 0;
    __syncthreads();

    unsigned start = (unsigned)bk * (unsigned)CAP;
    unsigned end = min(cursor[(size_t)bk * CSTRIDE], start + (unsigned)CAP);
    unsigned n = end - start;
    unsigned n8 = n >> 3;
    const uint4* e4 = reinterpret_cast<const uint4*>(entries + start);

    for (unsigned t = threadIdx.x; t < n8; t += ABLOCK) {
        uint4 a = e4[2 * t];
        uint4 b = e4[2 * t + 1];
        unsigned v0 = sq[a.x >> BUCKET_BITS];
        unsigned v1 = sq[a.y >> BUCKET_BITS];
        unsigned v2 = sq[a.z >> BUCKET_BITS];
        unsigned v3 = sq[a.w >> BUCKET_BITS];
        unsigned v4 = sq[b.x >> BUCKET_BITS];
        unsigned v5 = sq[b.y >> BUCKET_BITS];
        unsigned v6 = sq[b.z >> BUCKET_BITS];
        unsigned v7 = sq[b.w >> BUCKET_BITS];
        atomicAdd(&sbin[a.x & (BUCKET_NODES - 1)], v0);
        atomicAdd(&sbin[a.y & (BUCKET_NODES - 1)], v1);
        atomicAdd(&sbin[a.z & (BUCKET_NODES - 1)], v2);
        atomicAdd(&sbin[a.w & (BUCKET_NODES - 1)], v3);
        atomicAdd(&sbin[b.x & (BUCKET_NODES - 1)], v4);
        atomicAdd(&sbin[b.y & (BUCKET_NODES - 1)], v5);
        atomicAdd(&sbin[b.z & (BUCKET_NODES - 1)], v6);
        atomicAdd(&sbin[b.w & (BUCKET_NODES - 1)], v7);
    }
    for (unsigned t = start + (n8 << 3) + threadIdx.x; t < end; t += ABLOCK) {
        unsigned en = entries[t];
        atomicAdd(&sbin[en & (BUCKET_NODES - 1)], (unsigned)sq[en >> BUCKET_BITS]);
    }
    __syncthreads();

    int nodebase = bk << BUCKET_BITS;
    for (int il = threadIdx.x; il < BUCKET_NODES; il += ABLOCK) {
        int i = nodebase + il;
        if (i >= N) continue;
        float2 tgv = tg[i];
        float t = (float)(int)sbin[il] * tgv.x + tgv.y;
        out[i] = 1.0f / (1.0f + expf(-t));
    }
}

// ------------------- fallback (simple atomic path, 10MB ws) -----------------
__global__ __launch_bounds__(256) void k_scatter1_fb(
    const int* __restrict__ src, const int* __restrict__ dst,
    const float* __restrict__ x, float* __restrict__ agg1, float* __restrict__ deg, int E)
{
    int stride = gridDim.x * blockDim.x;
    for (int e = blockIdx.x * blockDim.x + threadIdx.x; e < E; e += stride) {
        int s = src[e], d = dst[e];
        float2 xv = *reinterpret_cast<const float2*>(x + 2 * (size_t)s);
        unsafeAtomicAdd(&agg1[2 * (size_t)d + 0], xv.x);
        unsafeAtomicAdd(&agg1[2 * (size_t)d + 1], xv.y);
        unsafeAtomicAdd(&deg[d], 1.0f);
    }
}
__global__ __launch_bounds__(256) void k_node1_fb(
    const float* __restrict__ x, const float* __restrict__ agg1, const float* __restrict__ deg,
    const float* __restrict__ W1l, const float* __restrict__ b1,
    const float* __restrict__ W1r, const float* __restrict__ W2l,
    float* __restrict__ sval, int N)
{
    int i = blockIdx.x * blockDim.x + threadIdx.x;
    if (i >= N) return;
    float inv = 1.0f / fmaxf(deg[i], 1.0f);
    float2 a = *reinterpret_cast<const float2*>(agg1 + 2 * (size_t)i);
    float m0 = a.x * inv, m1 = a.y * inv;
    float2 xv = *reinterpret_cast<const float2*>(x + 2 * (size_t)i);
    float s = 0.0f;
#pragma unroll
    for (int o = 0; o < 16; ++o) {
        float h = m0 * W1l[2 * o] + m1 * W1l[2 * o + 1] + b1[o]
                + xv.x * W1r[2 * o] + xv.y * W1r[2 * o + 1];
        s += fmaxf(h, 0.0f) * W2l[o];
    }
    sval[i] = s;
}
__global__ __launch_bounds__(256) void k_scatter2_fb(
    const int* __restrict__ src, const int* __restrict__ dst,
    const float* __restrict__ sval, float* __restrict__ agg_s, int E)
{
    int stride = gridDim.x * blockDim.x;
    for (int e = blockIdx.x * blockDim.x + threadIdx.x; e < E; e += stride)
        unsafeAtomicAdd(&agg_s[dst[e]], sval[src[e]]);
}
__global__ __launch_bounds__(256) void k_node2_fb(
    const float* __restrict__ x, const float* __restrict__ agg1, const float* __restrict__ deg,
    const float* __restrict__ agg_s,
    const float* __restrict__ W1l, const float* __restrict__ b1,
    const float* __restrict__ W1r, const float* __restrict__ W2r, const float* __restrict__ b2,
    float* __restrict__ out, int N)
{
    int i = blockIdx.x * blockDim.x + threadIdx.x;
    if (i >= N) return;
    float inv = 1.0f / fmaxf(deg[i], 1.0f);
    float2 a = *reinterpret_cast<const float2*>(agg1 + 2 * (size_t)i);
    float m0 = a.x * inv, m1 = a.y * inv;
    float2 xv = *reinterpret_cast<const float2*>(x + 2 * (size_t)i);
    float t = agg_s[i] * inv + b2[0];
#pragma unroll
    for (int o = 0; o < 16; ++o) {
        float h = m0 * W1l[2 * o] + m1 * W1l[2 * o + 1] + b1[o]
                + xv.x * W1r[2 * o] + xv.y * W1r[2 * o + 1];
        t += fmaxf(h, 0.0f) * W2r[o];
    }
    out[i] = 1.0f / (1.0f + expf(-t));
}

extern "C" void kernel_launch(void* const* d_in, const int* in_sizes, int n_in,
                              void* d_out, int out_size, void* d_ws, size_t ws_size,
                              hipStream_t stream) {
    const float* x   = (const float*)d_in[0];
    const int*   ei  = (const int*)d_in[1];
    const float* W1l = (const float*)d_in[2];
    const float* b1  = (const float*)d_in[3];
    const float* W1r = (const float*)d_in[4];
    const float* W2l = (const float*)d_in[5];
    const float* b2  = (const float*)d_in[6];
    const float* W2r = (const float*)d_in[7];

    const int N = in_sizes[0] / 2;
    const int E = in_sizes[1] / 2;
    const int* src = ei;
    const int* dst = ei + (size_t)E;
    float* out = (float*)d_out;

    const int NB = (N + BUCKET_NODES - 1) >> BUCKET_BITS;   // 489
    const int pblocks = (E + CHUNK - 1) / CHUNK;            // 245

    // ws: cursor[512*16] | entries[NB*CAP] | sq u16[N] | tg float2[N] | qx[N]
    size_t needed = (size_t)MAXNB * CSTRIDE * 4
                  + (size_t)NB * CAP * 4
                  + (((size_t)N * 2 + 7) & ~7ull)
                  + (size_t)N * 8 + (size_t)N * 4 + 256;
    if (NB <= MAXNB && NB <= PBLOCK && ws_size >= needed) {
        unsigned* cursor   = (unsigned*)d_ws;
        unsigned* entries  = cursor + (size_t)MAXNB * CSTRIDE;
        unsigned short* sq = (unsigned short*)(entries + (size_t)NB * CAP);
        float2*   tg       = (float2*)((char*)sq + (((size_t)N * 2 + 7) & ~7ull));
        unsigned* qx       = (unsigned*)(tg + N);

        k_pre<<<(N + 255) / 256, 256, 0, stream>>>(x, qx, cursor, N, NB);
        k_part<<<pblocks, PBLOCK, 0, stream>>>(src, dst, cursor, entries, E, NB);
        k_agg1<<<NB, ABLOCK, 0, stream>>>(entries, cursor, qx, x, W1l, b1, W1r,
                                          W2l, W2r, b2, sq, tg, N);
        k_agg2<<<NB, ABLOCK, 0, stream>>>(entries, cursor, sq, tg, out, N);
    } else {
        float* agg1  = (float*)d_ws;
        float* deg   = agg1 + 2 * (size_t)N;
        float* agg_s = deg + (size_t)N;
        float* sval  = agg_s + (size_t)N;
        hipMemsetAsync(d_ws, 0, 4 * (size_t)N * sizeof(float), stream);
        const int eblocks = 2048, nblocks = (N + 255) / 256;
        k_scatter1_fb<<<eblocks, 256, 0, stream>>>(src, dst, x, agg1, deg, E);
        k_node1_fb<<<nblocks, 256, 0, stream>>>(x, agg1, deg, W1l, b1, W1r, W2l, sval, N);
        k_scatter2_fb<<<eblocks, 256, 0, stream>>>(src, dst, sval, agg_s, E);
        k_node2_fb<<<nblocks, 256, 0, stream>>>(x, agg1, deg, agg_s, W1l, b1, W1r, W2r, b2, out, N);
    }
}